// Round 2
// baseline (534.275 us; speedup 1.0000x reference)
//
#include <hip/hip_runtime.h>
#include <hip/hip_bf16.h>
#include <cstdint>
#include <cstddef>

#define T_TOKENS 8192
#define DM 4096
#define NE 8
#define RANK 64

// ws layout (bytes):
//   [0, 64)        int cnt[16]              (slot*8 + e)
//   [1024, +512K)  int lists[2][8][8192]
//   [525312,+64K)  float wts[8192][2]
//   [1M, +8M)      float zpart[2][8192][2][64]   (k-split partials of x@A^T)
//   [10M, +2M)     ushort zbf[8192][2][64]        (weight-folded, bf16)
#define WS_CNT 0
#define WS_LISTS 1024
#define WS_WTS (WS_LISTS + 2 * 8 * 8192 * 4)
#define WS_ZPART (1 << 20)
#define WS_ZBF (10 << 20)
#define ZP (8192 * 2 * 64)

typedef __attribute__((ext_vector_type(8))) short bfrag;
typedef __attribute__((ext_vector_type(4))) float f4acc;

__device__ __forceinline__ unsigned short f2bf(float f) {
    unsigned int u = __float_as_uint(f);
    return (unsigned short)((u + 0x7FFF + ((u >> 16) & 1)) >> 16);
}

__global__ __launch_bounds__(64) void zero_cnt_kernel(int* __restrict__ cnt) {
    if (threadIdx.x < 16) cnt[threadIdx.x] = 0;
}

// Gate v3: no LDS (gw is 128KB, L1/L2-resident since every wave reads the
// same 8 float4s per step). 256 threads/block -> no occupancy cap; unroll 2
// keeps live x-values at 32 VGPRs -> no scratch spills. Wave = 4 tokens,
// 64 lanes read distinct contiguous float4s of x. fp32 throughout.
__global__ __launch_bounds__(256) void gate_kernel(
    const float* __restrict__ x, const float* __restrict__ gw,
    int* __restrict__ cnt, int* __restrict__ lists, float* __restrict__ wts) {
    int tid = threadIdx.x;
    int wave = tid >> 6, lane = tid & 63;
    int t0 = (blockIdx.x * 4 + wave) * 4;  // 512 blocks x 4 waves x 4 tokens

    float acc[4][8];
#pragma unroll
    for (int tt = 0; tt < 4; ++tt)
#pragma unroll
        for (int e = 0; e < 8; ++e) acc[tt][e] = 0.f;

    // lane covers float4 at offset lane*4 + i*256 floats of each row
    const float* xb = x + (size_t)t0 * DM + lane * 4;
    const float* gb = gw + lane * 4;
#pragma unroll 2
    for (int i = 0; i < 16; ++i) {
        float4 xv0 = *(const float4*)(xb + 0 * DM + i * 256);
        float4 xv1 = *(const float4*)(xb + 1 * DM + i * 256);
        float4 xv2 = *(const float4*)(xb + 2 * DM + i * 256);
        float4 xv3 = *(const float4*)(xb + 3 * DM + i * 256);
#pragma unroll
        for (int e = 0; e < 8; ++e) {
            float4 gv = *(const float4*)(gb + (size_t)e * DM + i * 256);
            acc[0][e] = fmaf(xv0.x, gv.x, acc[0][e]);
            acc[0][e] = fmaf(xv0.y, gv.y, acc[0][e]);
            acc[0][e] = fmaf(xv0.z, gv.z, acc[0][e]);
            acc[0][e] = fmaf(xv0.w, gv.w, acc[0][e]);
            acc[1][e] = fmaf(xv1.x, gv.x, acc[1][e]);
            acc[1][e] = fmaf(xv1.y, gv.y, acc[1][e]);
            acc[1][e] = fmaf(xv1.z, gv.z, acc[1][e]);
            acc[1][e] = fmaf(xv1.w, gv.w, acc[1][e]);
            acc[2][e] = fmaf(xv2.x, gv.x, acc[2][e]);
            acc[2][e] = fmaf(xv2.y, gv.y, acc[2][e]);
            acc[2][e] = fmaf(xv2.z, gv.z, acc[2][e]);
            acc[2][e] = fmaf(xv2.w, gv.w, acc[2][e]);
            acc[3][e] = fmaf(xv3.x, gv.x, acc[3][e]);
            acc[3][e] = fmaf(xv3.y, gv.y, acc[3][e]);
            acc[3][e] = fmaf(xv3.z, gv.z, acc[3][e]);
            acc[3][e] = fmaf(xv3.w, gv.w, acc[3][e]);
        }
    }

    // full-wave butterfly reduce: every lane ends with the complete sums
#pragma unroll
    for (int tt = 0; tt < 4; ++tt)
#pragma unroll
        for (int e = 0; e < 8; ++e) {
            float v = acc[tt][e];
            v += __shfl_xor(v, 1, 64);
            v += __shfl_xor(v, 2, 64);
            v += __shfl_xor(v, 4, 64);
            v += __shfl_xor(v, 8, 64);
            v += __shfl_xor(v, 16, 64);
            v += __shfl_xor(v, 32, 64);
            acc[tt][e] = v;
        }

    // lanes 0..3 each finalize one token (compile-time indexed selects)
    float l8[8];
#pragma unroll
    for (int e = 0; e < 8; ++e) {
        float v = acc[0][e];
        v = (lane == 1) ? acc[1][e] : v;
        v = (lane == 2) ? acc[2][e] : v;
        v = (lane == 3) ? acc[3][e] : v;
        l8[e] = v;
    }
    if (lane < 4) {
        int t = t0 + lane;
        float m = l8[0];
#pragma unroll
        for (int j = 1; j < 8; ++j) m = fmaxf(m, l8[j]);
        float p[8];
#pragma unroll
        for (int j = 0; j < 8; ++j) p[j] = expf(l8[j] - m);
        int e0 = 0;
        float p0 = p[0];
#pragma unroll
        for (int j = 1; j < 8; ++j)
            if (p[j] > p0) { p0 = p[j]; e0 = j; }
        int e1 = -1;
        float p1 = -1.0f;
#pragma unroll
        for (int j = 0; j < 8; ++j)
            if (j != e0 && p[j] > p1) { p1 = p[j]; e1 = j; }
        float inv = 1.0f / (p0 + p1);
        wts[t * 2 + 0] = p0 * inv;
        wts[t * 2 + 1] = p1 * inv;
        int pos0 = atomicAdd(&cnt[e0], 1);
        lists[(0 * 8 + e0) * T_TOKENS + pos0] = t;
        int pos1 = atomicAdd(&cnt[8 + e1], 1);
        lists[(1 * 8 + e1) * T_TOKENS + pos1] = t;
    }
}

// Phase A (MFMA): zpart[kh][t][slot][r] = x[t, kh-half] @ A_e[r, kh-half]^T
// Block: M=64 gathered tokens x N=64 ranks, K=2048 (half), BK=128. 4 waves.
#define TILES_A 20
#define BKA 128
#define PITCH_A 136  // 128 + 8 bf16 pad -> 2-way LDS read conflicts (free)
__global__ __launch_bounds__(256) void lora_a_mfma(
    const float* __restrict__ x, const float* __restrict__ A,
    const int* __restrict__ cnt, const int* __restrict__ lists,
    float* __restrict__ zpart) {
    int e = blockIdx.y;
    int sk = blockIdx.z;
    int slot = sk >> 1, kh = sk & 1;
    int count = cnt[slot * 8 + e];

    __shared__ __attribute__((aligned(16))) unsigned short xs[64 * PITCH_A];
    __shared__ __attribute__((aligned(16))) unsigned short as[64 * PITCH_A];
    __shared__ int stok[64];

    int tid = threadIdx.x;
    int wave = tid >> 6, lane = tid & 63;
    int q = lane >> 4, col = lane & 15;
    int srow = tid >> 2, sc = tid & 3;  // staging: row, 32-k chunk
    const int listbase = (slot * 8 + e) * T_TOKENS;
    float* zout = zpart + (size_t)kh * ZP;

    for (int ti = blockIdx.x; ti * 64 < count; ti += TILES_A) {
        int t0 = ti * 64;
        __syncthreads();
        if (tid < 64) {
            int idx = t0 + tid;
            stok[tid] = (idx < count) ? lists[listbase + idx] : lists[listbase];
        }
        __syncthreads();

        const float* xrow = x + (size_t)stok[srow] * DM + kh * 2048 + sc * 32;
        const float* arow = A + ((size_t)e * RANK + srow) * DM + kh * 2048 + sc * 32;

        f4acc acc[4] = {};

        for (int kb = 0; kb < 2048; kb += BKA) {
            __syncthreads();
            // stage x-tile and A-tile (fp32 -> bf16 during staging)
#pragma unroll
            for (int j = 0; j < 4; ++j) {
                float4 v0 = *(const float4*)(xrow + kb + j * 8);
                float4 v1 = *(const float4*)(xrow + kb + j * 8 + 4);
                unsigned short tmp[8] = {f2bf(v0.x), f2bf(v0.y), f2bf(v0.z), f2bf(v0.w),
                                         f2bf(v1.x), f2bf(v1.y), f2bf(v1.z), f2bf(v1.w)};
                *(bfrag*)&xs[srow * PITCH_A + sc * 32 + j * 8] = *(bfrag*)tmp;
                float4 w0 = *(const float4*)(arow + kb + j * 8);
                float4 w1 = *(const float4*)(arow + kb + j * 8 + 4);
                unsigned short tm2[8] = {f2bf(w0.x), f2bf(w0.y), f2bf(w0.z), f2bf(w0.w),
                                         f2bf(w1.x), f2bf(w1.y), f2bf(w1.z), f2bf(w1.w)};
                *(bfrag*)&as[srow * PITCH_A + sc * 32 + j * 8] = *(bfrag*)tm2;
            }
            __syncthreads();
#pragma unroll
            for (int ks = 0; ks < BKA / 32; ++ks) {
                bfrag af = *(const bfrag*)&xs[(wave * 16 + col) * PITCH_A + ks * 32 + q * 8];
#pragma unroll
                for (int nt = 0; nt < 4; ++nt) {
                    bfrag bf = *(const bfrag*)&as[(nt * 16 + col) * PITCH_A + ks * 32 + q * 8];
                    acc[nt] = __builtin_amdgcn_mfma_f32_16x16x32_bf16(af, bf, acc[nt], 0, 0, 0);
                }
            }
        }
        // D layout: row = q*4 + reg, col = lane&15
#pragma unroll
        for (int nt = 0; nt < 4; ++nt) {
#pragma unroll
            for (int r = 0; r < 4; ++r) {
                int mm = wave * 16 + q * 4 + r;
                if (t0 + mm < count) {
                    int tk = stok[mm];
                    zout[((size_t)tk * 2 + slot) * RANK + nt * 16 + col] = acc[nt][r];
                }
            }
        }
    }
}

// Reduce k-split partials, fold routing weight, emit bf16 z.
__global__ __launch_bounds__(256) void zreduce_kernel(
    const float* __restrict__ zpart, const float* __restrict__ wts,
    unsigned short* __restrict__ zbf) {
    int i = blockIdx.x * 256 + threadIdx.x;  // over 262144 float4 groups
    float4 a = ((const float4*)zpart)[i];
    float4 b = ((const float4*)(zpart + ZP))[i];
    float w = wts[i >> 4];
    ushort4 o;
    o.x = f2bf((a.x + b.x) * w);
    o.y = f2bf((a.y + b.y) * w);
    o.z = f2bf((a.z + b.z) * w);
    o.w = f2bf((a.w + b.w) * w);
    ((ushort4*)zbf)[i] = o;
}

// Phase B (MFMA): out[t][d] (+)= z_bf16[t][slot] . B_e[d][:]. M=64 tokens x N=128 d, K=64.
#define TILES_B2 16
#define PITCH_B 72  // 64 + 8 bf16 pad
__global__ __launch_bounds__(256) void lora_b_mfma(
    const unsigned short* __restrict__ zbf, const float* __restrict__ B,
    const int* __restrict__ cnt, const int* __restrict__ lists,
    float* __restrict__ out, int slot) {
    int e = blockIdx.z;
    int count = cnt[slot * 8 + e];
    int d0 = blockIdx.x * 128;

    __shared__ __attribute__((aligned(16))) unsigned short zs[64 * PITCH_B];
    __shared__ __attribute__((aligned(16))) unsigned short bs[128 * PITCH_B];
    __shared__ int stok[64];

    int tid = threadIdx.x;
    int wave = tid >> 6, lane = tid & 63;
    int q = lane >> 4, col = lane & 15;
    const int listbase = (slot * 8 + e) * T_TOKENS;

    // stage B tile once (constant across token tiles): row = tid>>1, half = tid&1
    {
        int row = tid >> 1, h = tid & 1;
        const float* bp = B + ((size_t)e * DM + d0 + row) * RANK + h * 32;
#pragma unroll
        for (int j = 0; j < 4; ++j) {
            float4 v0 = *(const float4*)(bp + j * 8);
            float4 v1 = *(const float4*)(bp + j * 8 + 4);
            unsigned short tmp[8] = {f2bf(v0.x), f2bf(v0.y), f2bf(v0.z), f2bf(v0.w),
                                     f2bf(v1.x), f2bf(v1.y), f2bf(v1.z), f2bf(v1.w)};
            *(bfrag*)&bs[row * PITCH_B + h * 32 + j * 8] = *(bfrag*)tmp;
        }
    }

    for (int ti = blockIdx.y; ti * 64 < count; ti += TILES_B2) {
        int t0 = ti * 64;
        __syncthreads();
        if (tid < 64) {
            int idx = t0 + tid;
            stok[tid] = (idx < count) ? lists[listbase + idx] : -1;
        }
        __syncthreads();
        // stage z tile: row = tid>>2, 16-bf16 chunk c = tid&3
        {
            int row = tid >> 2, c = tid & 3;
            int tk = stok[row];
            int tkc = tk < 0 ? 0 : tk;
            const uint4* zp = (const uint4*)(zbf + ((size_t)tkc * 2 + slot) * RANK + c * 16);
            uint4 v0 = zp[0];
            uint4 v1 = zp[1];
            *(uint4*)&zs[row * PITCH_B + c * 16] = v0;
            *(uint4*)&zs[row * PITCH_B + c * 16 + 8] = v1;
        }
        __syncthreads();

        f4acc acc[8] = {};
#pragma unroll
        for (int ks = 0; ks < 2; ++ks) {
            bfrag af = *(const bfrag*)&zs[(wave * 16 + col) * PITCH_B + ks * 32 + q * 8];
#pragma unroll
            for (int nt = 0; nt < 8; ++nt) {
                bfrag bf = *(const bfrag*)&bs[(nt * 16 + col) * PITCH_B + ks * 32 + q * 8];
                acc[nt] = __builtin_amdgcn_mfma_f32_16x16x32_bf16(af, bf, acc[nt], 0, 0, 0);
            }
        }
#pragma unroll
        for (int r = 0; r < 4; ++r) {
            int mm = wave * 16 + q * 4 + r;
            int tk = stok[mm];
            if (tk >= 0) {
                float* op = out + (size_t)tk * DM + d0 + col;
                if (slot == 0) {
#pragma unroll
                    for (int nt = 0; nt < 8; ++nt) op[nt * 16] = acc[nt][r];
                } else {
#pragma unroll
                    for (int nt = 0; nt < 8; ++nt) op[nt * 16] += acc[nt][r];
                }
            }
        }
    }
}

extern "C" void kernel_launch(void* const* d_in, const int* in_sizes, int n_in,
                              void* d_out, int out_size, void* d_ws, size_t ws_size,
                              hipStream_t stream) {
    const float* x = (const float*)d_in[0];
    const float* gw = (const float*)d_in[1];
    const float* A = (const float*)d_in[2];
    const float* Bm = (const float*)d_in[3];
    float* out = (float*)d_out;
    char* ws = (char*)d_ws;
    int* cnt = (int*)(ws + WS_CNT);
    int* lists = (int*)(ws + WS_LISTS);
    float* wts = (float*)(ws + WS_WTS);
    float* zpart = (float*)(ws + WS_ZPART);
    unsigned short* zbf = (unsigned short*)(ws + WS_ZBF);

    zero_cnt_kernel<<<1, 64, 0, stream>>>(cnt);
    gate_kernel<<<512, 256, 0, stream>>>(x, gw, cnt, lists, wts);
    lora_a_mfma<<<dim3(TILES_A, 8, 4), 256, 0, stream>>>(x, A, cnt, lists, zpart);
    zreduce_kernel<<<1024, 256, 0, stream>>>(zpart, wts, zbf);
    lora_b_mfma<<<dim3(32, TILES_B2, 8), 256, 0, stream>>>(zbf, Bm, cnt, lists, out, 0);
    lora_b_mfma<<<dim3(32, TILES_B2, 8), 256, 0, stream>>>(zbf, Bm, cnt, lists, out, 1);
}

// Round 3
// 516.768 us; speedup vs baseline: 1.0339x; 1.0339x over previous
//
#include <hip/hip_runtime.h>
#include <hip/hip_bf16.h>
#include <cstdint>
#include <cstddef>

#define T_TOKENS 8192
#define DM 4096
#define NE 8
#define RANK 64

// ws layout (bytes):
//   [0, 64)        int cnt[16]              (slot*8 + e)
//   [1024, +512K)  int lists[2][8][8192]
//   [525312,+64K)  float wts[8192][2]
//   [1M, +8M)      float zpart[2][8192][2][64]   (k-split partials of x@A^T)
//   [10M, +2M)     ushort zbf[8192][2][64]        (weight-folded, bf16)
#define WS_CNT 0
#define WS_LISTS 1024
#define WS_WTS (WS_LISTS + 2 * 8 * 8192 * 4)
#define WS_ZPART (1 << 20)
#define WS_ZBF (10 << 20)
#define ZP (8192 * 2 * 64)

typedef __attribute__((ext_vector_type(8))) short bfrag;
typedef __attribute__((ext_vector_type(4))) float f4acc;

__device__ __forceinline__ unsigned short f2bf(float f) {
    unsigned int u = __float_as_uint(f);
    return (unsigned short)((u + 0x7FFF + ((u >> 16) & 1)) >> 16);
}

__global__ __launch_bounds__(64) void zero_cnt_kernel(int* __restrict__ cnt) {
    if (threadIdx.x < 16) cnt[threadIdx.x] = 0;
}

// Gate v4: split-K. Block = 4 waves x 4 tokens; wave w covers k-quarter
// [w*1024, w*1024+1024). 2048 blocks x 4 waves = 8192 waves = 32/CU (max
// occupancy; v3's 19% grid-limited occupancy was the latency bottleneck).
// Partials combined via 512B LDS; fp32 throughout (top-k exactness).
__global__ __launch_bounds__(256) void gate_kernel(
    const float* __restrict__ x, const float* __restrict__ gw,
    int* __restrict__ cnt, int* __restrict__ lists, float* __restrict__ wts) {
    int tid = threadIdx.x;
    int wave = tid >> 6, lane = tid & 63;
    int t0 = blockIdx.x * 4;

    float acc[4][8];
#pragma unroll
    for (int tt = 0; tt < 4; ++tt)
#pragma unroll
        for (int e = 0; e < 8; ++e) acc[tt][e] = 0.f;

    // lane covers float4 at offset wave*1024 + i*256 + lane*4 of each row
    const float* xb = x + (size_t)t0 * DM + wave * 1024 + lane * 4;
    const float* gb = gw + wave * 1024 + lane * 4;
#pragma unroll 2
    for (int i = 0; i < 4; ++i) {
        float4 xv0 = *(const float4*)(xb + 0 * DM + i * 256);
        float4 xv1 = *(const float4*)(xb + 1 * DM + i * 256);
        float4 xv2 = *(const float4*)(xb + 2 * DM + i * 256);
        float4 xv3 = *(const float4*)(xb + 3 * DM + i * 256);
#pragma unroll
        for (int e = 0; e < 8; ++e) {
            float4 gv = *(const float4*)(gb + (size_t)e * DM + i * 256);
            acc[0][e] = fmaf(xv0.x, gv.x, acc[0][e]);
            acc[0][e] = fmaf(xv0.y, gv.y, acc[0][e]);
            acc[0][e] = fmaf(xv0.z, gv.z, acc[0][e]);
            acc[0][e] = fmaf(xv0.w, gv.w, acc[0][e]);
            acc[1][e] = fmaf(xv1.x, gv.x, acc[1][e]);
            acc[1][e] = fmaf(xv1.y, gv.y, acc[1][e]);
            acc[1][e] = fmaf(xv1.z, gv.z, acc[1][e]);
            acc[1][e] = fmaf(xv1.w, gv.w, acc[1][e]);
            acc[2][e] = fmaf(xv2.x, gv.x, acc[2][e]);
            acc[2][e] = fmaf(xv2.y, gv.y, acc[2][e]);
            acc[2][e] = fmaf(xv2.z, gv.z, acc[2][e]);
            acc[2][e] = fmaf(xv2.w, gv.w, acc[2][e]);
            acc[3][e] = fmaf(xv3.x, gv.x, acc[3][e]);
            acc[3][e] = fmaf(xv3.y, gv.y, acc[3][e]);
            acc[3][e] = fmaf(xv3.z, gv.z, acc[3][e]);
            acc[3][e] = fmaf(xv3.w, gv.w, acc[3][e]);
        }
    }

    // full-wave butterfly reduce: every lane ends with the complete quarter-sums
#pragma unroll
    for (int tt = 0; tt < 4; ++tt)
#pragma unroll
        for (int e = 0; e < 8; ++e) {
            float v = acc[tt][e];
            v += __shfl_xor(v, 1, 64);
            v += __shfl_xor(v, 2, 64);
            v += __shfl_xor(v, 4, 64);
            v += __shfl_xor(v, 8, 64);
            v += __shfl_xor(v, 16, 64);
            v += __shfl_xor(v, 32, 64);
            acc[tt][e] = v;
        }

    // lanes 0..3 each hold one token's 8 partials (compile-time selects)
    float l8[8];
#pragma unroll
    for (int e = 0; e < 8; ++e) {
        float v = acc[0][e];
        v = (lane == 1) ? acc[1][e] : v;
        v = (lane == 2) ? acc[2][e] : v;
        v = (lane == 3) ? acc[3][e] : v;
        l8[e] = v;
    }

    __shared__ float part[4][4][8];  // [wave][token][expert]
    if (lane < 4) {
#pragma unroll
        for (int e = 0; e < 8; ++e) part[wave][lane][e] = l8[e];
    }
    __syncthreads();

    if (tid < 4) {
        int t = t0 + tid;
        float s8[8];
#pragma unroll
        for (int e = 0; e < 8; ++e)
            s8[e] = ((part[0][tid][e] + part[1][tid][e]) +
                     (part[2][tid][e] + part[3][tid][e]));
        float m = s8[0];
#pragma unroll
        for (int j = 1; j < 8; ++j) m = fmaxf(m, s8[j]);
        float p[8];
#pragma unroll
        for (int j = 0; j < 8; ++j) p[j] = expf(s8[j] - m);
        int e0 = 0;
        float p0 = p[0];
#pragma unroll
        for (int j = 1; j < 8; ++j)
            if (p[j] > p0) { p0 = p[j]; e0 = j; }
        int e1 = -1;
        float p1 = -1.0f;
#pragma unroll
        for (int j = 0; j < 8; ++j)
            if (j != e0 && p[j] > p1) { p1 = p[j]; e1 = j; }
        float inv = 1.0f / (p0 + p1);
        wts[t * 2 + 0] = p0 * inv;
        wts[t * 2 + 1] = p1 * inv;
        int pos0 = atomicAdd(&cnt[e0], 1);
        lists[(0 * 8 + e0) * T_TOKENS + pos0] = t;
        int pos1 = atomicAdd(&cnt[8 + e1], 1);
        lists[(1 * 8 + e1) * T_TOKENS + pos1] = t;
    }
}

// Phase A (MFMA): zpart[kh][t][slot][r] = x[t, kh-half] @ A_e[r, kh-half]^T
// Block: M=64 gathered tokens x N=64 ranks, K=2048 (half), BK=128. 4 waves.
#define TILES_A 20
#define BKA 128
#define PITCH_A 136  // 128 + 8 bf16 pad -> 2-way LDS read conflicts (free)
__global__ __launch_bounds__(256) void lora_a_mfma(
    const float* __restrict__ x, const float* __restrict__ A,
    const int* __restrict__ cnt, const int* __restrict__ lists,
    float* __restrict__ zpart) {
    int e = blockIdx.y;
    int sk = blockIdx.z;
    int slot = sk >> 1, kh = sk & 1;
    int count = cnt[slot * 8 + e];

    __shared__ __attribute__((aligned(16))) unsigned short xs[64 * PITCH_A];
    __shared__ __attribute__((aligned(16))) unsigned short as[64 * PITCH_A];
    __shared__ int stok[64];

    int tid = threadIdx.x;
    int wave = tid >> 6, lane = tid & 63;
    int q = lane >> 4, col = lane & 15;
    int srow = tid >> 2, sc = tid & 3;  // staging: row, 32-k chunk
    const int listbase = (slot * 8 + e) * T_TOKENS;
    float* zout = zpart + (size_t)kh * ZP;

    for (int ti = blockIdx.x; ti * 64 < count; ti += TILES_A) {
        int t0 = ti * 64;
        __syncthreads();
        if (tid < 64) {
            int idx = t0 + tid;
            stok[tid] = (idx < count) ? lists[listbase + idx] : lists[listbase];
        }
        __syncthreads();

        const float* xrow = x + (size_t)stok[srow] * DM + kh * 2048 + sc * 32;
        const float* arow = A + ((size_t)e * RANK + srow) * DM + kh * 2048 + sc * 32;

        f4acc acc[4] = {};

        for (int kb = 0; kb < 2048; kb += BKA) {
            __syncthreads();
            // stage x-tile and A-tile (fp32 -> bf16 during staging)
#pragma unroll
            for (int j = 0; j < 4; ++j) {
                float4 v0 = *(const float4*)(xrow + kb + j * 8);
                float4 v1 = *(const float4*)(xrow + kb + j * 8 + 4);
                unsigned short tmp[8] = {f2bf(v0.x), f2bf(v0.y), f2bf(v0.z), f2bf(v0.w),
                                         f2bf(v1.x), f2bf(v1.y), f2bf(v1.z), f2bf(v1.w)};
                *(bfrag*)&xs[srow * PITCH_A + sc * 32 + j * 8] = *(bfrag*)tmp;
                float4 w0 = *(const float4*)(arow + kb + j * 8);
                float4 w1 = *(const float4*)(arow + kb + j * 8 + 4);
                unsigned short tm2[8] = {f2bf(w0.x), f2bf(w0.y), f2bf(w0.z), f2bf(w0.w),
                                         f2bf(w1.x), f2bf(w1.y), f2bf(w1.z), f2bf(w1.w)};
                *(bfrag*)&as[srow * PITCH_A + sc * 32 + j * 8] = *(bfrag*)tm2;
            }
            __syncthreads();
#pragma unroll
            for (int ks = 0; ks < BKA / 32; ++ks) {
                bfrag af = *(const bfrag*)&xs[(wave * 16 + col) * PITCH_A + ks * 32 + q * 8];
#pragma unroll
                for (int nt = 0; nt < 4; ++nt) {
                    bfrag bf = *(const bfrag*)&as[(nt * 16 + col) * PITCH_A + ks * 32 + q * 8];
                    acc[nt] = __builtin_amdgcn_mfma_f32_16x16x32_bf16(af, bf, acc[nt], 0, 0, 0);
                }
            }
        }
        // D layout: row = q*4 + reg, col = lane&15
#pragma unroll
        for (int nt = 0; nt < 4; ++nt) {
#pragma unroll
            for (int r = 0; r < 4; ++r) {
                int mm = wave * 16 + q * 4 + r;
                if (t0 + mm < count) {
                    int tk = stok[mm];
                    zout[((size_t)tk * 2 + slot) * RANK + nt * 16 + col] = acc[nt][r];
                }
            }
        }
    }
}

// Reduce k-split partials, fold routing weight, emit bf16 z.
__global__ __launch_bounds__(256) void zreduce_kernel(
    const float* __restrict__ zpart, const float* __restrict__ wts,
    unsigned short* __restrict__ zbf) {
    int i = blockIdx.x * 256 + threadIdx.x;  // over 262144 float4 groups
    float4 a = ((const float4*)zpart)[i];
    float4 b = ((const float4*)(zpart + ZP))[i];
    float w = wts[i >> 4];
    ushort4 o;
    o.x = f2bf((a.x + b.x) * w);
    o.y = f2bf((a.y + b.y) * w);
    o.z = f2bf((a.z + b.z) * w);
    o.w = f2bf((a.w + b.w) * w);
    ((ushort4*)zbf)[i] = o;
}

// Phase B (MFMA): out[t][d] (+)= z_bf16[t][slot] . B_e[d][:]. M=64 tokens x N=128 d, K=64.
#define TILES_B2 16
#define PITCH_B 72  // 64 + 8 bf16 pad
__global__ __launch_bounds__(256) void lora_b_mfma(
    const unsigned short* __restrict__ zbf, const float* __restrict__ B,
    const int* __restrict__ cnt, const int* __restrict__ lists,
    float* __restrict__ out, int slot) {
    int e = blockIdx.z;
    int count = cnt[slot * 8 + e];
    int d0 = blockIdx.x * 128;

    __shared__ __attribute__((aligned(16))) unsigned short zs[64 * PITCH_B];
    __shared__ __attribute__((aligned(16))) unsigned short bs[128 * PITCH_B];
    __shared__ int stok[64];

    int tid = threadIdx.x;
    int wave = tid >> 6, lane = tid & 63;
    int q = lane >> 4, col = lane & 15;
    const int listbase = (slot * 8 + e) * T_TOKENS;

    // stage B tile once (constant across token tiles): row = tid>>1, half = tid&1
    {
        int row = tid >> 1, h = tid & 1;
        const float* bp = B + ((size_t)e * DM + d0 + row) * RANK + h * 32;
#pragma unroll
        for (int j = 0; j < 4; ++j) {
            float4 v0 = *(const float4*)(bp + j * 8);
            float4 v1 = *(const float4*)(bp + j * 8 + 4);
            unsigned short tmp[8] = {f2bf(v0.x), f2bf(v0.y), f2bf(v0.z), f2bf(v0.w),
                                     f2bf(v1.x), f2bf(v1.y), f2bf(v1.z), f2bf(v1.w)};
            *(bfrag*)&bs[row * PITCH_B + h * 32 + j * 8] = *(bfrag*)tmp;
        }
    }

    for (int ti = blockIdx.y; ti * 64 < count; ti += TILES_B2) {
        int t0 = ti * 64;
        __syncthreads();
        if (tid < 64) {
            int idx = t0 + tid;
            stok[tid] = (idx < count) ? lists[listbase + idx] : -1;
        }
        __syncthreads();
        // stage z tile: row = tid>>2, 16-bf16 chunk c = tid&3
        {
            int row = tid >> 2, c = tid & 3;
            int tk = stok[row];
            int tkc = tk < 0 ? 0 : tk;
            const uint4* zp = (const uint4*)(zbf + ((size_t)tkc * 2 + slot) * RANK + c * 16);
            uint4 v0 = zp[0];
            uint4 v1 = zp[1];
            *(uint4*)&zs[row * PITCH_B + c * 16] = v0;
            *(uint4*)&zs[row * PITCH_B + c * 16 + 8] = v1;
        }
        __syncthreads();

        f4acc acc[8] = {};
#pragma unroll
        for (int ks = 0; ks < 2; ++ks) {
            bfrag af = *(const bfrag*)&zs[(wave * 16 + col) * PITCH_B + ks * 32 + q * 8];
#pragma unroll
            for (int nt = 0; nt < 8; ++nt) {
                bfrag bf = *(const bfrag*)&bs[(nt * 16 + col) * PITCH_B + ks * 32 + q * 8];
                acc[nt] = __builtin_amdgcn_mfma_f32_16x16x32_bf16(af, bf, acc[nt], 0, 0, 0);
            }
        }
#pragma unroll
        for (int r = 0; r < 4; ++r) {
            int mm = wave * 16 + q * 4 + r;
            int tk = stok[mm];
            if (tk >= 0) {
                float* op = out + (size_t)tk * DM + d0 + col;
                if (slot == 0) {
#pragma unroll
                    for (int nt = 0; nt < 8; ++nt) op[nt * 16] = acc[nt][r];
                } else {
#pragma unroll
                    for (int nt = 0; nt < 8; ++nt) op[nt * 16] += acc[nt][r];
                }
            }
        }
    }
}

extern "C" void kernel_launch(void* const* d_in, const int* in_sizes, int n_in,
                              void* d_out, int out_size, void* d_ws, size_t ws_size,
                              hipStream_t stream) {
    const float* x = (const float*)d_in[0];
    const float* gw = (const float*)d_in[1];
    const float* A = (const float*)d_in[2];
    const float* Bm = (const float*)d_in[3];
    float* out = (float*)d_out;
    char* ws = (char*)d_ws;
    int* cnt = (int*)(ws + WS_CNT);
    int* lists = (int*)(ws + WS_LISTS);
    float* wts = (float*)(ws + WS_WTS);
    float* zpart = (float*)(ws + WS_ZPART);
    unsigned short* zbf = (unsigned short*)(ws + WS_ZBF);

    zero_cnt_kernel<<<1, 64, 0, stream>>>(cnt);
    gate_kernel<<<2048, 256, 0, stream>>>(x, gw, cnt, lists, wts);
    lora_a_mfma<<<dim3(TILES_A, 8, 4), 256, 0, stream>>>(x, A, cnt, lists, zpart);
    zreduce_kernel<<<1024, 256, 0, stream>>>(zpart, wts, zbf);
    lora_b_mfma<<<dim3(32, TILES_B2, 8), 256, 0, stream>>>(zbf, Bm, cnt, lists, out, 0);
    lora_b_mfma<<<dim3(32, TILES_B2, 8), 256, 0, stream>>>(zbf, Bm, cnt, lists, out, 1);
}

// Round 4
// 479.596 us; speedup vs baseline: 1.1140x; 1.0775x over previous
//
#include <hip/hip_runtime.h>
#include <hip/hip_bf16.h>
#include <cstdint>
#include <cstddef>

#define T_TOKENS 8192
#define DM 4096
#define NE 8
#define RANK 64

// ws layout (bytes):
//   [0, 64)        int cnt[16]              (slot*8 + e)
//   [1024, +512K)  int lists[2][8][8192]
//   [525312,+64K)  float wts[8192][2]
//   [590848,+16K)  ushort selp[8192]         (e0 | e1<<8, per token)
//   [1M, +8M)      float zpart[2][8192][2][64]   (k-split partials of x@A^T)
//   [10M, +2M)     ushort zbf[8192][2][64]        (weight-folded, bf16)
#define WS_CNT 0
#define WS_LISTS 1024
#define WS_WTS (WS_LISTS + 2 * 8 * 8192 * 4)
#define WS_SELP (WS_WTS + 8192 * 2 * 4)
#define WS_ZPART (1 << 20)
#define WS_ZBF (10 << 20)
#define ZP (8192 * 2 * 64)

typedef __attribute__((ext_vector_type(8))) short bfrag;
typedef __attribute__((ext_vector_type(4))) float f4acc;

__device__ __forceinline__ unsigned short f2bf(float f) {
    unsigned int u = __float_as_uint(f);
    return (unsigned short)((u + 0x7FFF + ((u >> 16) & 1)) >> 16);
}

// Gate v5 phase 1: split-K logits + top-2, ZERO global atomics.
// Block = 4 waves x 4 tokens; wave w covers k-quarter [w*1024, +1024).
// 2048 blocks -> 32 waves/CU. Emits wts[t] and packed selp[t] only.
// (v2..v4 all pinned at 125-142us regardless of occupancy: the shared floor
//  was 16K device-scope atomicAdds on 16 counters. Removed entirely here.)
__global__ __launch_bounds__(256) void gate_kernel(
    const float* __restrict__ x, const float* __restrict__ gw,
    unsigned short* __restrict__ selp, float* __restrict__ wts) {
    int tid = threadIdx.x;
    int wave = tid >> 6, lane = tid & 63;
    int t0 = blockIdx.x * 4;

    float acc[4][8];
#pragma unroll
    for (int tt = 0; tt < 4; ++tt)
#pragma unroll
        for (int e = 0; e < 8; ++e) acc[tt][e] = 0.f;

    const float* xb = x + (size_t)t0 * DM + wave * 1024 + lane * 4;
    const float* gb = gw + wave * 1024 + lane * 4;
#pragma unroll 2
    for (int i = 0; i < 4; ++i) {
        float4 xv0 = *(const float4*)(xb + 0 * DM + i * 256);
        float4 xv1 = *(const float4*)(xb + 1 * DM + i * 256);
        float4 xv2 = *(const float4*)(xb + 2 * DM + i * 256);
        float4 xv3 = *(const float4*)(xb + 3 * DM + i * 256);
#pragma unroll
        for (int e = 0; e < 8; ++e) {
            float4 gv = *(const float4*)(gb + (size_t)e * DM + i * 256);
            acc[0][e] = fmaf(xv0.x, gv.x, acc[0][e]);
            acc[0][e] = fmaf(xv0.y, gv.y, acc[0][e]);
            acc[0][e] = fmaf(xv0.z, gv.z, acc[0][e]);
            acc[0][e] = fmaf(xv0.w, gv.w, acc[0][e]);
            acc[1][e] = fmaf(xv1.x, gv.x, acc[1][e]);
            acc[1][e] = fmaf(xv1.y, gv.y, acc[1][e]);
            acc[1][e] = fmaf(xv1.z, gv.z, acc[1][e]);
            acc[1][e] = fmaf(xv1.w, gv.w, acc[1][e]);
            acc[2][e] = fmaf(xv2.x, gv.x, acc[2][e]);
            acc[2][e] = fmaf(xv2.y, gv.y, acc[2][e]);
            acc[2][e] = fmaf(xv2.z, gv.z, acc[2][e]);
            acc[2][e] = fmaf(xv2.w, gv.w, acc[2][e]);
            acc[3][e] = fmaf(xv3.x, gv.x, acc[3][e]);
            acc[3][e] = fmaf(xv3.y, gv.y, acc[3][e]);
            acc[3][e] = fmaf(xv3.z, gv.z, acc[3][e]);
            acc[3][e] = fmaf(xv3.w, gv.w, acc[3][e]);
        }
    }

    // full-wave butterfly reduce: every lane ends with the complete quarter-sums
#pragma unroll
    for (int tt = 0; tt < 4; ++tt)
#pragma unroll
        for (int e = 0; e < 8; ++e) {
            float v = acc[tt][e];
            v += __shfl_xor(v, 1, 64);
            v += __shfl_xor(v, 2, 64);
            v += __shfl_xor(v, 4, 64);
            v += __shfl_xor(v, 8, 64);
            v += __shfl_xor(v, 16, 64);
            v += __shfl_xor(v, 32, 64);
            acc[tt][e] = v;
        }

    // lanes 0..3 each hold one token's 8 partials (compile-time selects)
    float l8[8];
#pragma unroll
    for (int e = 0; e < 8; ++e) {
        float v = acc[0][e];
        v = (lane == 1) ? acc[1][e] : v;
        v = (lane == 2) ? acc[2][e] : v;
        v = (lane == 3) ? acc[3][e] : v;
        l8[e] = v;
    }

    __shared__ float part[4][4][8];  // [wave][token][expert]
    if (lane < 4) {
#pragma unroll
        for (int e = 0; e < 8; ++e) part[wave][lane][e] = l8[e];
    }
    __syncthreads();

    if (tid < 4) {
        int t = t0 + tid;
        float s8[8];
#pragma unroll
        for (int e = 0; e < 8; ++e)
            s8[e] = ((part[0][tid][e] + part[1][tid][e]) +
                     (part[2][tid][e] + part[3][tid][e]));
        float m = s8[0];
#pragma unroll
        for (int j = 1; j < 8; ++j) m = fmaxf(m, s8[j]);
        float p[8];
#pragma unroll
        for (int j = 0; j < 8; ++j) p[j] = expf(s8[j] - m);
        int e0 = 0;
        float p0 = p[0];
#pragma unroll
        for (int j = 1; j < 8; ++j)
            if (p[j] > p0) { p0 = p[j]; e0 = j; }
        int e1 = -1;
        float p1 = -1.0f;
#pragma unroll
        for (int j = 0; j < 8; ++j)
            if (j != e0 && p[j] > p1) { p1 = p[j]; e1 = j; }
        float inv = 1.0f / (p0 + p1);
        wts[t * 2 + 0] = p0 * inv;
        wts[t * 2 + 1] = p1 * inv;
        selp[t] = (unsigned short)(e0 | (e1 << 8));
    }
}

// Gate v5 phase 2: build per-(slot,expert) token lists. 16 blocks, each owns
// one list + its cnt entry: scan selp (16KB, L2-hot), ballot-compact matches,
// one LDS atomic per wave-iteration. No global atomics anywhere.
__global__ __launch_bounds__(256) void build_lists(
    const unsigned short* __restrict__ selp,
    int* __restrict__ cnt, int* __restrict__ lists) {
    int b = blockIdx.x;          // b = slot*8 + e
    int slot = b >> 3, e = b & 7;
    __shared__ int base;
    if (threadIdx.x == 0) base = 0;
    __syncthreads();
    int lane = threadIdx.x & 63, wv = threadIdx.x >> 6;
    int* listp = lists + b * T_TOKENS;
    int shift = slot * 8;
    for (int it = 0; it < T_TOKENS / 256; ++it) {
        int t = it * 256 + wv * 64 + lane;
        int ev = (selp[t] >> shift) & 255;
        bool mt = (ev == e);
        unsigned long long mask = __ballot(mt);
        int cw = __popcll(mask);
        int wbase = 0;
        if (lane == 0 && cw) wbase = atomicAdd(&base, cw);
        wbase = __shfl(wbase, 0, 64);
        if (mt) {
            int pos = __popcll(mask & ((1ull << lane) - 1ull));
            listp[wbase + pos] = t;
        }
    }
    __syncthreads();
    if (threadIdx.x == 0) cnt[b] = base;
}

// Phase A (MFMA): zpart[kh][t][slot][r] = x[t, kh-half] @ A_e[r, kh-half]^T
// Block: M=64 gathered tokens x N=64 ranks, K=2048 (half), BK=128. 4 waves.
#define TILES_A 20
#define BKA 128
#define PITCH_A 136  // 128 + 8 bf16 pad -> 2-way LDS read conflicts (free)
__global__ __launch_bounds__(256) void lora_a_mfma(
    const float* __restrict__ x, const float* __restrict__ A,
    const int* __restrict__ cnt, const int* __restrict__ lists,
    float* __restrict__ zpart) {
    int e = blockIdx.y;
    int sk = blockIdx.z;
    int slot = sk >> 1, kh = sk & 1;
    int count = cnt[slot * 8 + e];

    __shared__ __attribute__((aligned(16))) unsigned short xs[64 * PITCH_A];
    __shared__ __attribute__((aligned(16))) unsigned short as[64 * PITCH_A];
    __shared__ int stok[64];

    int tid = threadIdx.x;
    int wave = tid >> 6, lane = tid & 63;
    int q = lane >> 4, col = lane & 15;
    int srow = tid >> 2, sc = tid & 3;  // staging: row, 32-k chunk
    const int listbase = (slot * 8 + e) * T_TOKENS;
    float* zout = zpart + (size_t)kh * ZP;

    for (int ti = blockIdx.x; ti * 64 < count; ti += TILES_A) {
        int t0 = ti * 64;
        __syncthreads();
        if (tid < 64) {
            int idx = t0 + tid;
            stok[tid] = (idx < count) ? lists[listbase + idx] : lists[listbase];
        }
        __syncthreads();

        const float* xrow = x + (size_t)stok[srow] * DM + kh * 2048 + sc * 32;
        const float* arow = A + ((size_t)e * RANK + srow) * DM + kh * 2048 + sc * 32;

        f4acc acc[4] = {};

        for (int kb = 0; kb < 2048; kb += BKA) {
            __syncthreads();
            // stage x-tile and A-tile (fp32 -> bf16 during staging)
#pragma unroll
            for (int j = 0; j < 4; ++j) {
                float4 v0 = *(const float4*)(xrow + kb + j * 8);
                float4 v1 = *(const float4*)(xrow + kb + j * 8 + 4);
                unsigned short tmp[8] = {f2bf(v0.x), f2bf(v0.y), f2bf(v0.z), f2bf(v0.w),
                                         f2bf(v1.x), f2bf(v1.y), f2bf(v1.z), f2bf(v1.w)};
                *(bfrag*)&xs[srow * PITCH_A + sc * 32 + j * 8] = *(bfrag*)tmp;
                float4 w0 = *(const float4*)(arow + kb + j * 8);
                float4 w1 = *(const float4*)(arow + kb + j * 8 + 4);
                unsigned short tm2[8] = {f2bf(w0.x), f2bf(w0.y), f2bf(w0.z), f2bf(w0.w),
                                         f2bf(w1.x), f2bf(w1.y), f2bf(w1.z), f2bf(w1.w)};
                *(bfrag*)&as[srow * PITCH_A + sc * 32 + j * 8] = *(bfrag*)tm2;
            }
            __syncthreads();
#pragma unroll
            for (int ks = 0; ks < BKA / 32; ++ks) {
                bfrag af = *(const bfrag*)&xs[(wave * 16 + col) * PITCH_A + ks * 32 + q * 8];
#pragma unroll
                for (int nt = 0; nt < 4; ++nt) {
                    bfrag bf = *(const bfrag*)&as[(nt * 16 + col) * PITCH_A + ks * 32 + q * 8];
                    acc[nt] = __builtin_amdgcn_mfma_f32_16x16x32_bf16(af, bf, acc[nt], 0, 0, 0);
                }
            }
        }
        // D layout: row = q*4 + reg, col = lane&15
#pragma unroll
        for (int nt = 0; nt < 4; ++nt) {
#pragma unroll
            for (int r = 0; r < 4; ++r) {
                int mm = wave * 16 + q * 4 + r;
                if (t0 + mm < count) {
                    int tk = stok[mm];
                    zout[((size_t)tk * 2 + slot) * RANK + nt * 16 + col] = acc[nt][r];
                }
            }
        }
    }
}

// Reduce k-split partials, fold routing weight, emit bf16 z.
__global__ __launch_bounds__(256) void zreduce_kernel(
    const float* __restrict__ zpart, const float* __restrict__ wts,
    unsigned short* __restrict__ zbf) {
    int i = blockIdx.x * 256 + threadIdx.x;  // over 262144 float4 groups
    float4 a = ((const float4*)zpart)[i];
    float4 b = ((const float4*)(zpart + ZP))[i];
    float w = wts[i >> 4];
    ushort4 o;
    o.x = f2bf((a.x + b.x) * w);
    o.y = f2bf((a.y + b.y) * w);
    o.z = f2bf((a.z + b.z) * w);
    o.w = f2bf((a.w + b.w) * w);
    ((ushort4*)zbf)[i] = o;
}

// Phase B (MFMA): out[t][d] (+)= z_bf16[t][slot] . B_e[d][:]. M=64 tokens x N=128 d, K=64.
#define TILES_B2 16
#define PITCH_B 72  // 64 + 8 bf16 pad
__global__ __launch_bounds__(256) void lora_b_mfma(
    const unsigned short* __restrict__ zbf, const float* __restrict__ B,
    const int* __restrict__ cnt, const int* __restrict__ lists,
    float* __restrict__ out, int slot) {
    int e = blockIdx.z;
    int count = cnt[slot * 8 + e];
    int d0 = blockIdx.x * 128;

    __shared__ __attribute__((aligned(16))) unsigned short zs[64 * PITCH_B];
    __shared__ __attribute__((aligned(16))) unsigned short bs[128 * PITCH_B];
    __shared__ int stok[64];

    int tid = threadIdx.x;
    int wave = tid >> 6, lane = tid & 63;
    int q = lane >> 4, col = lane & 15;
    const int listbase = (slot * 8 + e) * T_TOKENS;

    // stage B tile once (constant across token tiles): row = tid>>1, half = tid&1
    {
        int row = tid >> 1, h = tid & 1;
        const float* bp = B + ((size_t)e * DM + d0 + row) * RANK + h * 32;
#pragma unroll
        for (int j = 0; j < 4; ++j) {
            float4 v0 = *(const float4*)(bp + j * 8);
            float4 v1 = *(const float4*)(bp + j * 8 + 4);
            unsigned short tmp[8] = {f2bf(v0.x), f2bf(v0.y), f2bf(v0.z), f2bf(v0.w),
                                     f2bf(v1.x), f2bf(v1.y), f2bf(v1.z), f2bf(v1.w)};
            *(bfrag*)&bs[row * PITCH_B + h * 32 + j * 8] = *(bfrag*)tmp;
        }
    }

    for (int ti = blockIdx.y; ti * 64 < count; ti += TILES_B2) {
        int t0 = ti * 64;
        __syncthreads();
        if (tid < 64) {
            int idx = t0 + tid;
            stok[tid] = (idx < count) ? lists[listbase + idx] : -1;
        }
        __syncthreads();
        // stage z tile: row = tid>>2, 16-bf16 chunk c = tid&3
        {
            int row = tid >> 2, c = tid & 3;
            int tk = stok[row];
            int tkc = tk < 0 ? 0 : tk;
            const uint4* zp = (const uint4*)(zbf + ((size_t)tkc * 2 + slot) * RANK + c * 16);
            uint4 v0 = zp[0];
            uint4 v1 = zp[1];
            *(uint4*)&zs[row * PITCH_B + c * 16] = v0;
            *(uint4*)&zs[row * PITCH_B + c * 16 + 8] = v1;
        }
        __syncthreads();

        f4acc acc[8] = {};
#pragma unroll
        for (int ks = 0; ks < 2; ++ks) {
            bfrag af = *(const bfrag*)&zs[(wave * 16 + col) * PITCH_B + ks * 32 + q * 8];
#pragma unroll
            for (int nt = 0; nt < 8; ++nt) {
                bfrag bf = *(const bfrag*)&bs[(nt * 16 + col) * PITCH_B + ks * 32 + q * 8];
                acc[nt] = __builtin_amdgcn_mfma_f32_16x16x32_bf16(af, bf, acc[nt], 0, 0, 0);
            }
        }
#pragma unroll
        for (int r = 0; r < 4; ++r) {
            int mm = wave * 16 + q * 4 + r;
            int tk = stok[mm];
            if (tk >= 0) {
                float* op = out + (size_t)tk * DM + d0 + col;
                if (slot == 0) {
#pragma unroll
                    for (int nt = 0; nt < 8; ++nt) op[nt * 16] = acc[nt][r];
                } else {
#pragma unroll
                    for (int nt = 0; nt < 8; ++nt) op[nt * 16] += acc[nt][r];
                }
            }
        }
    }
}

extern "C" void kernel_launch(void* const* d_in, const int* in_sizes, int n_in,
                              void* d_out, int out_size, void* d_ws, size_t ws_size,
                              hipStream_t stream) {
    const float* x = (const float*)d_in[0];
    const float* gw = (const float*)d_in[1];
    const float* A = (const float*)d_in[2];
    const float* Bm = (const float*)d_in[3];
    float* out = (float*)d_out;
    char* ws = (char*)d_ws;
    int* cnt = (int*)(ws + WS_CNT);
    int* lists = (int*)(ws + WS_LISTS);
    float* wts = (float*)(ws + WS_WTS);
    unsigned short* selp = (unsigned short*)(ws + WS_SELP);
    float* zpart = (float*)(ws + WS_ZPART);
    unsigned short* zbf = (unsigned short*)(ws + WS_ZBF);

    gate_kernel<<<2048, 256, 0, stream>>>(x, gw, selp, wts);
    build_lists<<<16, 256, 0, stream>>>(selp, cnt, lists);
    lora_a_mfma<<<dim3(TILES_A, 8, 4), 256, 0, stream>>>(x, A, cnt, lists, zpart);
    zreduce_kernel<<<1024, 256, 0, stream>>>(zpart, wts, zbf);
    lora_b_mfma<<<dim3(32, TILES_B2, 8), 256, 0, stream>>>(zbf, Bm, cnt, lists, out, 0);
    lora_b_mfma<<<dim3(32, TILES_B2, 8), 256, 0, stream>>>(zbf, Bm, cnt, lists, out, 1);
}

// Round 5
// 398.192 us; speedup vs baseline: 1.3418x; 1.2044x over previous
//
#include <hip/hip_runtime.h>
#include <hip/hip_bf16.h>
#include <cstdint>
#include <cstddef>

#define T_TOKENS 8192
#define DM 4096
#define NE 8
#define RANK 64

// ws layout (bytes):
//   [0, 64)        int cnt[16]              (slot*8 + e)
//   [1024, +512K)  int lists[2][8][8192]
//   [525312,+64K)  float wts[8192][2]
//   [590848,+16K)  ushort selp[8192]         (e0 | e1<<8, per token)
//   fast path (ws >= 76MB):
//     [1M, +4M)    ushort abf[8][64][4096]    (bf16 A)
//     [5M, +4M)    ushort bbf[8][4096][64]    (bf16 B)
//     [10M, +2M)   ushort zbf[8192][2][64]    (weight-folded, bf16)
//     [12M, +64M)  ushort xbf[8192][4096]     (bf16 x, emitted by gate)
//   fallback (old R4 path):
//     [1M, +8M)    float zpart[2][8192][2][64]
//     [10M, +2M)   ushort zbf
#define WS_CNT 0
#define WS_LISTS 1024
#define WS_WTS (WS_LISTS + 2 * 8 * 8192 * 4)
#define WS_SELP (WS_WTS + 8192 * 2 * 4)
#define WS_ABF (1 << 20)
#define WS_BBF (5 << 20)
#define WS_ZPART (1 << 20)
#define WS_ZBF (10 << 20)
#define WS_XBF (12 << 20)
#define WS_NEED_FAST ((size_t)(12 << 20) + (size_t)T_TOKENS * DM * 2)
#define ZP (8192 * 2 * 64)

typedef __attribute__((ext_vector_type(8))) short bfrag;
typedef __attribute__((ext_vector_type(4))) float f4acc;

__device__ __forceinline__ unsigned short f2bf(float f) {
    unsigned int u = __float_as_uint(f);
    return (unsigned short)((u + 0x7FFF + ((u >> 16) & 1)) >> 16);
}

// Gate: split-K logits + top-2, zero global atomics (R4, confirmed win).
// Optionally emits xbf (bf16 copy of x) for the fast lora_a path — gate
// already streams all of x, so the cast is free VALU + 64MB of writes.
__global__ __launch_bounds__(256) void gate_kernel(
    const float* __restrict__ x, const float* __restrict__ gw,
    unsigned short* __restrict__ selp, float* __restrict__ wts,
    unsigned short* __restrict__ xbf) {
    int tid = threadIdx.x;
    int wave = tid >> 6, lane = tid & 63;
    int t0 = blockIdx.x * 4;

    float acc[4][8];
#pragma unroll
    for (int tt = 0; tt < 4; ++tt)
#pragma unroll
        for (int e = 0; e < 8; ++e) acc[tt][e] = 0.f;

    const float* xb = x + (size_t)t0 * DM + wave * 1024 + lane * 4;
    const float* gb = gw + wave * 1024 + lane * 4;
#pragma unroll 2
    for (int i = 0; i < 4; ++i) {
        float4 xv0 = *(const float4*)(xb + 0 * DM + i * 256);
        float4 xv1 = *(const float4*)(xb + 1 * DM + i * 256);
        float4 xv2 = *(const float4*)(xb + 2 * DM + i * 256);
        float4 xv3 = *(const float4*)(xb + 3 * DM + i * 256);
        if (xbf) {
            size_t xo = (size_t)t0 * DM + wave * 1024 + i * 256 + lane * 4;
            ushort4 o0 = {f2bf(xv0.x), f2bf(xv0.y), f2bf(xv0.z), f2bf(xv0.w)};
            ushort4 o1 = {f2bf(xv1.x), f2bf(xv1.y), f2bf(xv1.z), f2bf(xv1.w)};
            ushort4 o2 = {f2bf(xv2.x), f2bf(xv2.y), f2bf(xv2.z), f2bf(xv2.w)};
            ushort4 o3 = {f2bf(xv3.x), f2bf(xv3.y), f2bf(xv3.z), f2bf(xv3.w)};
            *(ushort4*)(xbf + xo + 0 * DM) = o0;
            *(ushort4*)(xbf + xo + 1 * DM) = o1;
            *(ushort4*)(xbf + xo + 2 * DM) = o2;
            *(ushort4*)(xbf + xo + 3 * DM) = o3;
        }
#pragma unroll
        for (int e = 0; e < 8; ++e) {
            float4 gv = *(const float4*)(gb + (size_t)e * DM + i * 256);
            acc[0][e] = fmaf(xv0.x, gv.x, acc[0][e]);
            acc[0][e] = fmaf(xv0.y, gv.y, acc[0][e]);
            acc[0][e] = fmaf(xv0.z, gv.z, acc[0][e]);
            acc[0][e] = fmaf(xv0.w, gv.w, acc[0][e]);
            acc[1][e] = fmaf(xv1.x, gv.x, acc[1][e]);
            acc[1][e] = fmaf(xv1.y, gv.y, acc[1][e]);
            acc[1][e] = fmaf(xv1.z, gv.z, acc[1][e]);
            acc[1][e] = fmaf(xv1.w, gv.w, acc[1][e]);
            acc[2][e] = fmaf(xv2.x, gv.x, acc[2][e]);
            acc[2][e] = fmaf(xv2.y, gv.y, acc[2][e]);
            acc[2][e] = fmaf(xv2.z, gv.z, acc[2][e]);
            acc[2][e] = fmaf(xv2.w, gv.w, acc[2][e]);
            acc[3][e] = fmaf(xv3.x, gv.x, acc[3][e]);
            acc[3][e] = fmaf(xv3.y, gv.y, acc[3][e]);
            acc[3][e] = fmaf(xv3.z, gv.z, acc[3][e]);
            acc[3][e] = fmaf(xv3.w, gv.w, acc[3][e]);
        }
    }

#pragma unroll
    for (int tt = 0; tt < 4; ++tt)
#pragma unroll
        for (int e = 0; e < 8; ++e) {
            float v = acc[tt][e];
            v += __shfl_xor(v, 1, 64);
            v += __shfl_xor(v, 2, 64);
            v += __shfl_xor(v, 4, 64);
            v += __shfl_xor(v, 8, 64);
            v += __shfl_xor(v, 16, 64);
            v += __shfl_xor(v, 32, 64);
            acc[tt][e] = v;
        }

    float l8[8];
#pragma unroll
    for (int e = 0; e < 8; ++e) {
        float v = acc[0][e];
        v = (lane == 1) ? acc[1][e] : v;
        v = (lane == 2) ? acc[2][e] : v;
        v = (lane == 3) ? acc[3][e] : v;
        l8[e] = v;
    }

    __shared__ float part[4][4][8];  // [wave][token][expert]
    if (lane < 4) {
#pragma unroll
        for (int e = 0; e < 8; ++e) part[wave][lane][e] = l8[e];
    }
    __syncthreads();

    if (tid < 4) {
        int t = t0 + tid;
        float s8[8];
#pragma unroll
        for (int e = 0; e < 8; ++e)
            s8[e] = ((part[0][tid][e] + part[1][tid][e]) +
                     (part[2][tid][e] + part[3][tid][e]));
        float m = s8[0];
#pragma unroll
        for (int j = 1; j < 8; ++j) m = fmaxf(m, s8[j]);
        float p[8];
#pragma unroll
        for (int j = 0; j < 8; ++j) p[j] = expf(s8[j] - m);
        int e0 = 0;
        float p0 = p[0];
#pragma unroll
        for (int j = 1; j < 8; ++j)
            if (p[j] > p0) { p0 = p[j]; e0 = j; }
        int e1 = -1;
        float p1 = -1.0f;
#pragma unroll
        for (int j = 0; j < 8; ++j)
            if (j != e0 && p[j] > p1) { p1 = p[j]; e1 = j; }
        float inv = 1.0f / (p0 + p1);
        wts[t * 2 + 0] = p0 * inv;
        wts[t * 2 + 1] = p1 * inv;
        selp[t] = (unsigned short)(e0 | (e1 << 8));
    }
}

// Build per-(slot,expert) token lists; LDS atomics only (R4, confirmed).
__global__ __launch_bounds__(256) void build_lists(
    const unsigned short* __restrict__ selp,
    int* __restrict__ cnt, int* __restrict__ lists) {
    int b = blockIdx.x;          // b = slot*8 + e
    int slot = b >> 3, e = b & 7;
    __shared__ int base;
    if (threadIdx.x == 0) base = 0;
    __syncthreads();
    int lane = threadIdx.x & 63, wv = threadIdx.x >> 6;
    int* listp = lists + b * T_TOKENS;
    int shift = slot * 8;
    for (int it = 0; it < T_TOKENS / 256; ++it) {
        int t = it * 256 + wv * 64 + lane;
        int ev = (selp[t] >> shift) & 255;
        bool mt = (ev == e);
        unsigned long long mask = __ballot(mt);
        int cw = __popcll(mask);
        int wbase = 0;
        if (lane == 0 && cw) wbase = atomicAdd(&base, cw);
        wbase = __shfl(wbase, 0, 64);
        if (mt) {
            int pos = __popcll(mask & ((1ull << lane) - 1ull));
            listp[wbase + pos] = t;
        }
    }
    __syncthreads();
    if (threadIdx.x == 0) cnt[b] = base;
}

// Cast A and B to bf16 once (16MB traffic, ~2us).
__global__ __launch_bounds__(256) void cast_ab(
    const float* __restrict__ A, const float* __restrict__ B,
    unsigned short* __restrict__ abf, unsigned short* __restrict__ bbf) {
    size_t o = ((size_t)blockIdx.x * 256 + threadIdx.x) * 8;  // 262144 threads x 8
    float4 a0 = ((const float4*)(A + o))[0];
    float4 a1 = ((const float4*)(A + o))[1];
    unsigned short ta[8] = {f2bf(a0.x), f2bf(a0.y), f2bf(a0.z), f2bf(a0.w),
                            f2bf(a1.x), f2bf(a1.y), f2bf(a1.z), f2bf(a1.w)};
    *(bfrag*)(abf + o) = *(bfrag*)ta;
    float4 b0 = ((const float4*)(B + o))[0];
    float4 b1 = ((const float4*)(B + o))[1];
    unsigned short tb[8] = {f2bf(b0.x), f2bf(b0.y), f2bf(b0.z), f2bf(b0.w),
                            f2bf(b1.x), f2bf(b1.y), f2bf(b1.z), f2bf(b1.w)};
    *(bfrag*)(bbf + o) = *(bfrag*)tb;
}

// Phase A v2: zbf[t][slot][r] = f2bf(wts[t][slot] * (xbf[t] @ abf[e]^T)).
// Full K=4096 (no k-split), bf16 source, global_load_lds staging into linear
// 64x128 LDS tiles with XOR-swizzled global source (rule #21: linear dest +
// inverse-swz source + swz read). Grid (128, e, slot): one 64-token tile per
// block -> natural balance; 4 blocks/CU by LDS (32.5KB).
__global__ __launch_bounds__(256) void lora_a_v2(
    const unsigned short* __restrict__ xbf, const unsigned short* __restrict__ abf,
    const int* __restrict__ cnt, const int* __restrict__ lists,
    const float* __restrict__ wts, unsigned short* __restrict__ zbf) {
    int e = blockIdx.y, slot = blockIdx.z;
    int count = cnt[slot * 8 + e];
    int ti = blockIdx.x;
    if (ti * 64 >= count) return;

    __shared__ __attribute__((aligned(16))) unsigned short xs2[64 * 128];
    __shared__ __attribute__((aligned(16))) unsigned short as2[64 * 128];
    __shared__ int stok[64];
    __shared__ float wv[64];

    int tid = threadIdx.x;
    int wave = tid >> 6, lane = tid & 63;
    int q = lane >> 4, col = lane & 15;
    const int listbase = (slot * 8 + e) * T_TOKENS;

    if (tid < 64) {
        int idx = ti * 64 + tid;
        stok[tid] = (idx < count) ? lists[listbase + idx] : lists[listbase];
    }
    __syncthreads();
    if (tid < 64) wv[tid] = wts[stok[tid] * 2 + slot];

    // staging geometry: instr i covers rows wave*16+i*4 .. +3 (1KB linear LDS).
    // lane -> row = +lane>>4, within-row byte (lane&15)*16, global src XOR-swz.
    const unsigned short* xg[4];
    const unsigned short* ag[4];
#pragma unroll
    for (int i = 0; i < 4; ++i) {
        int row = wave * 16 + i * 4 + (lane >> 4);
        int koff = (((lane & 15) * 16) ^ ((row & 7) << 4)) >> 1;  // shorts
        xg[i] = xbf + (size_t)stok[row] * DM + koff;
        ag[i] = abf + ((size_t)e * RANK + row) * DM + koff;
    }

    f4acc acc[4] = {};
    const unsigned short* xrl = xs2 + (wave * 16 + col) * 128;
    const unsigned short* arl = as2 + col * 128;
    int sx = (col & 7) << 4;  // read-side swizzle (bytes)

    for (int kb = 0; kb < DM; kb += 128) {
        __syncthreads();
#pragma unroll
        for (int i = 0; i < 4; ++i) {
            __builtin_amdgcn_global_load_lds(
                (const unsigned int*)(xg[i] + kb),
                (unsigned int*)&xs2[(wave * 16 + i * 4) * 128], 16, 0, 0);
            __builtin_amdgcn_global_load_lds(
                (const unsigned int*)(ag[i] + kb),
                (unsigned int*)&as2[(wave * 16 + i * 4) * 128], 16, 0, 0);
        }
        __syncthreads();  // drains vmcnt+lgkm before reads
#pragma unroll
        for (int ks = 0; ks < 4; ++ks) {
            int off = ((ks * 64 + q * 16) ^ sx) >> 1;  // shorts
            bfrag af = *(const bfrag*)(xrl + off);
#pragma unroll
            for (int nt = 0; nt < 4; ++nt) {
                bfrag bf = *(const bfrag*)(arl + nt * 2048 + off);
                acc[nt] = __builtin_amdgcn_mfma_f32_16x16x32_bf16(af, bf, acc[nt], 0, 0, 0);
            }
        }
    }
    // D layout: token row = wave*16 + q*4 + r, rank col = nt*16 + (lane&15)
#pragma unroll
    for (int nt = 0; nt < 4; ++nt) {
#pragma unroll
        for (int r = 0; r < 4; ++r) {
            int mm = wave * 16 + q * 4 + r;
            if (ti * 64 + mm < count) {
                zbf[((size_t)stok[mm] * 2 + slot) * RANK + nt * 16 + col] =
                    f2bf(acc[nt][r] * wv[mm]);
            }
        }
    }
}

// ---------------- fallback path (R4 kernels, used if ws too small) ----------
#define TILES_A 20
#define BKA 128
#define PITCH_A 136
__global__ __launch_bounds__(256) void lora_a_mfma(
    const float* __restrict__ x, const float* __restrict__ A,
    const int* __restrict__ cnt, const int* __restrict__ lists,
    float* __restrict__ zpart) {
    int e = blockIdx.y;
    int sk = blockIdx.z;
    int slot = sk >> 1, kh = sk & 1;
    int count = cnt[slot * 8 + e];

    __shared__ __attribute__((aligned(16))) unsigned short xs[64 * PITCH_A];
    __shared__ __attribute__((aligned(16))) unsigned short as[64 * PITCH_A];
    __shared__ int stok[64];

    int tid = threadIdx.x;
    int wave = tid >> 6, lane = tid & 63;
    int q = lane >> 4, col = lane & 15;
    int srow = tid >> 2, sc = tid & 3;
    const int listbase = (slot * 8 + e) * T_TOKENS;
    float* zout = zpart + (size_t)kh * ZP;

    for (int ti = blockIdx.x; ti * 64 < count; ti += TILES_A) {
        int t0 = ti * 64;
        __syncthreads();
        if (tid < 64) {
            int idx = t0 + tid;
            stok[tid] = (idx < count) ? lists[listbase + idx] : lists[listbase];
        }
        __syncthreads();

        const float* xrow = x + (size_t)stok[srow] * DM + kh * 2048 + sc * 32;
        const float* arow = A + ((size_t)e * RANK + srow) * DM + kh * 2048 + sc * 32;

        f4acc acc[4] = {};

        for (int kb = 0; kb < 2048; kb += BKA) {
            __syncthreads();
#pragma unroll
            for (int j = 0; j < 4; ++j) {
                float4 v0 = *(const float4*)(xrow + kb + j * 8);
                float4 v1 = *(const float4*)(xrow + kb + j * 8 + 4);
                unsigned short tmp[8] = {f2bf(v0.x), f2bf(v0.y), f2bf(v0.z), f2bf(v0.w),
                                         f2bf(v1.x), f2bf(v1.y), f2bf(v1.z), f2bf(v1.w)};
                *(bfrag*)&xs[srow * PITCH_A + sc * 32 + j * 8] = *(bfrag*)tmp;
                float4 w0 = *(const float4*)(arow + kb + j * 8);
                float4 w1 = *(const float4*)(arow + kb + j * 8 + 4);
                unsigned short tm2[8] = {f2bf(w0.x), f2bf(w0.y), f2bf(w0.z), f2bf(w0.w),
                                         f2bf(w1.x), f2bf(w1.y), f2bf(w1.z), f2bf(w1.w)};
                *(bfrag*)&as[srow * PITCH_A + sc * 32 + j * 8] = *(bfrag*)tm2;
            }
            __syncthreads();
#pragma unroll
            for (int ks = 0; ks < BKA / 32; ++ks) {
                bfrag af = *(const bfrag*)&xs[(wave * 16 + col) * PITCH_A + ks * 32 + q * 8];
#pragma unroll
                for (int nt = 0; nt < 4; ++nt) {
                    bfrag bf = *(const bfrag*)&as[(nt * 16 + col) * PITCH_A + ks * 32 + q * 8];
                    acc[nt] = __builtin_amdgcn_mfma_f32_16x16x32_bf16(af, bf, acc[nt], 0, 0, 0);
                }
            }
        }
#pragma unroll
        for (int nt = 0; nt < 4; ++nt) {
#pragma unroll
            for (int r = 0; r < 4; ++r) {
                int mm = wave * 16 + q * 4 + r;
                if (t0 + mm < count) {
                    int tk = stok[mm];
                    zout[((size_t)tk * 2 + slot) * RANK + nt * 16 + col] = acc[nt][r];
                }
            }
        }
    }
}

__global__ __launch_bounds__(256) void zreduce_kernel(
    const float* __restrict__ zpart, const float* __restrict__ wts,
    unsigned short* __restrict__ zbf) {
    int i = blockIdx.x * 256 + threadIdx.x;
    float4 a = ((const float4*)zpart)[i];
    float4 b = ((const float4*)(zpart + ZP))[i];
    float w = wts[i >> 4];
    ushort4 o;
    o.x = f2bf((a.x + b.x) * w);
    o.y = f2bf((a.y + b.y) * w);
    o.z = f2bf((a.z + b.z) * w);
    o.w = f2bf((a.w + b.w) * w);
    ((ushort4*)zbf)[i] = o;
}
// ---------------------------------------------------------------------------

// Phase B (MFMA): out[t][d] (+)= z_bf16[t][slot] . B_e[d][:]. M=64 x N=128, K=64.
// bbf != nullptr -> stage B from bf16 (no f2bf VALU); else fp32 fallback.
#define TILES_B2 16
#define PITCH_B 72
__global__ __launch_bounds__(256) void lora_b_mfma(
    const unsigned short* __restrict__ zbf, const float* __restrict__ B,
    const unsigned short* __restrict__ bbf,
    const int* __restrict__ cnt, const int* __restrict__ lists,
    float* __restrict__ out, int slot) {
    int e = blockIdx.z;
    int count = cnt[slot * 8 + e];
    int d0 = blockIdx.x * 128;

    __shared__ __attribute__((aligned(16))) unsigned short zs[64 * PITCH_B];
    __shared__ __attribute__((aligned(16))) unsigned short bs[128 * PITCH_B];
    __shared__ int stok[64];

    int tid = threadIdx.x;
    int wave = tid >> 6, lane = tid & 63;
    int q = lane >> 4, col = lane & 15;
    const int listbase = (slot * 8 + e) * T_TOKENS;

    {
        int row = tid >> 1, h = tid & 1;
        if (bbf) {
            const unsigned short* bp = bbf + ((size_t)e * DM + d0 + row) * RANK + h * 32;
#pragma unroll
            for (int j = 0; j < 4; ++j) {
                bfrag v = *(const bfrag*)(bp + j * 8);
                *(bfrag*)&bs[row * PITCH_B + h * 32 + j * 8] = v;
            }
        } else {
            const float* bp = B + ((size_t)e * DM + d0 + row) * RANK + h * 32;
#pragma unroll
            for (int j = 0; j < 4; ++j) {
                float4 v0 = *(const float4*)(bp + j * 8);
                float4 v1 = *(const float4*)(bp + j * 8 + 4);
                unsigned short tmp[8] = {f2bf(v0.x), f2bf(v0.y), f2bf(v0.z), f2bf(v0.w),
                                         f2bf(v1.x), f2bf(v1.y), f2bf(v1.z), f2bf(v1.w)};
                *(bfrag*)&bs[row * PITCH_B + h * 32 + j * 8] = *(bfrag*)tmp;
            }
        }
    }

    for (int ti = blockIdx.y; ti * 64 < count; ti += TILES_B2) {
        int t0 = ti * 64;
        __syncthreads();
        if (tid < 64) {
            int idx = t0 + tid;
            stok[tid] = (idx < count) ? lists[listbase + idx] : -1;
        }
        __syncthreads();
        {
            int row = tid >> 2, c = tid & 3;
            int tk = stok[row];
            int tkc = tk < 0 ? 0 : tk;
            const uint4* zp = (const uint4*)(zbf + ((size_t)tkc * 2 + slot) * RANK + c * 16);
            uint4 v0 = zp[0];
            uint4 v1 = zp[1];
            *(uint4*)&zs[row * PITCH_B + c * 16] = v0;
            *(uint4*)&zs[row * PITCH_B + c * 16 + 8] = v1;
        }
        __syncthreads();

        f4acc acc[8] = {};
#pragma unroll
        for (int ks = 0; ks < 2; ++ks) {
            bfrag af = *(const bfrag*)&zs[(wave * 16 + col) * PITCH_B + ks * 32 + q * 8];
#pragma unroll
            for (int nt = 0; nt < 8; ++nt) {
                bfrag bf = *(const bfrag*)&bs[(nt * 16 + col) * PITCH_B + ks * 32 + q * 8];
                acc[nt] = __builtin_amdgcn_mfma_f32_16x16x32_bf16(af, bf, acc[nt], 0, 0, 0);
            }
        }
#pragma unroll
        for (int r = 0; r < 4; ++r) {
            int mm = wave * 16 + q * 4 + r;
            int tk = stok[mm];
            if (tk >= 0) {
                float* op = out + (size_t)tk * DM + d0 + col;
                if (slot == 0) {
#pragma unroll
                    for (int nt = 0; nt < 8; ++nt) op[nt * 16] = acc[nt][r];
                } else {
#pragma unroll
                    for (int nt = 0; nt < 8; ++nt) op[nt * 16] += acc[nt][r];
                }
            }
        }
    }
}

extern "C" void kernel_launch(void* const* d_in, const int* in_sizes, int n_in,
                              void* d_out, int out_size, void* d_ws, size_t ws_size,
                              hipStream_t stream) {
    const float* x = (const float*)d_in[0];
    const float* gw = (const float*)d_in[1];
    const float* A = (const float*)d_in[2];
    const float* Bm = (const float*)d_in[3];
    float* out = (float*)d_out;
    char* ws = (char*)d_ws;
    int* cnt = (int*)(ws + WS_CNT);
    int* lists = (int*)(ws + WS_LISTS);
    float* wts = (float*)(ws + WS_WTS);
    unsigned short* selp = (unsigned short*)(ws + WS_SELP);
    unsigned short* zbf = (unsigned short*)(ws + WS_ZBF);

    if (ws_size >= WS_NEED_FAST) {
        unsigned short* abf = (unsigned short*)(ws + WS_ABF);
        unsigned short* bbf = (unsigned short*)(ws + WS_BBF);
        unsigned short* xbf = (unsigned short*)(ws + WS_XBF);
        gate_kernel<<<2048, 256, 0, stream>>>(x, gw, selp, wts, xbf);
        cast_ab<<<1024, 256, 0, stream>>>(A, Bm, abf, bbf);
        build_lists<<<16, 256, 0, stream>>>(selp, cnt, lists);
        lora_a_v2<<<dim3(128, 8, 2), 256, 0, stream>>>(xbf, abf, cnt, lists, wts, zbf);
        lora_b_mfma<<<dim3(32, TILES_B2, 8), 256, 0, stream>>>(zbf, Bm, bbf, cnt, lists, out, 0);
        lora_b_mfma<<<dim3(32, TILES_B2, 8), 256, 0, stream>>>(zbf, Bm, bbf, cnt, lists, out, 1);
    } else {
        float* zpart = (float*)(ws + WS_ZPART);
        gate_kernel<<<2048, 256, 0, stream>>>(x, gw, selp, wts, nullptr);
        build_lists<<<16, 256, 0, stream>>>(selp, cnt, lists);
        lora_a_mfma<<<dim3(TILES_A, 8, 4), 256, 0, stream>>>(x, A, cnt, lists, zpart);
        zreduce_kernel<<<1024, 256, 0, stream>>>(zpart, wts, zbf);
        lora_b_mfma<<<dim3(32, TILES_B2, 8), 256, 0, stream>>>(zbf, Bm, nullptr, cnt, lists, out, 0);
        lora_b_mfma<<<dim3(32, TILES_B2, 8), 256, 0, stream>>>(zbf, Bm, nullptr, cnt, lists, out, 1);
    }
}